// Round 8
// baseline (82.702 us; speedup 1.0000x reference)
//
#include <hip/hip_runtime.h>

// PatchChamferDistance: B=32, G=64, P=256, D=3 -> BG=2048 patches.
// dist2[i][j] = ||p_i||^2 + ||t_j||^2 - 2 p_i.t_j (clamped >= 0)
// out = mean over patches of (mean_i min_j + mean_j min_i)
//
// Round 8 = round 7 (MFMA, 81.1 us) + two VALU shaves:
//  - A/B fragments pre-converted to packed f16x8 in LDS at staging time:
//    per-ib A-frag build = one ds_read_b128 (was ~8 cvt/mul). A-frag quads
//    1-3 read the same point (finite * B's zero = 0, no cndmask); B-frag
//    quads 1-3 read a shared zeroed 16B slot (broadcast).
//  - jb unrolled x2 so rowmin uses v_min3 on two MFMA results:
//    8 min3 / 2 MFMAs (was 12 ops).
// Established: fusion attempts regress (r4 fence storm, r6 atomic bounce);
// two-kernel skeleton stays. C/D layout col=lane&15, row=quad*4+reg (m89).
// Numerics identical to r7 (f16 coords, tn hi+lo split, fp32 pn in C-init).

#define NPATCH 2048
#define NPTS   256

typedef _Float16 f16x8 __attribute__((ext_vector_type(8)));
typedef float    f32x4 __attribute__((ext_vector_type(4)));

__global__ __launch_bounds__(256, 2) void chamfer_mfma_kernel(
    const float* __restrict__ pred,
    const float* __restrict__ tgt,
    float* __restrict__ partial)
{
    __shared__ __align__(16) f16x8 sA[4][NPTS];   // pred A-frags
    __shared__ __align__(16) f16x8 sB[4][NPTS];   // tgt  B-frags
    __shared__ __align__(16) float sPn[4][NPTS];  // pred norms (C-init)
    __shared__ __align__(16) f16x8 szero;         // broadcast zero frag

    const int tid = threadIdx.x;

    // Stage 4 patches: convert once, whole block cooperates.
    {
        const size_t pbase = (size_t)blockIdx.x * 4 * (NPTS * 3);
#pragma unroll
        for (int pp = 0; pp < 4; ++pp) {
            const float* __restrict__ pb = pred + pbase + pp * (NPTS * 3);
            const float* __restrict__ tb = tgt  + pbase + pp * (NPTS * 3);
            float x = pb[3 * tid + 0], y = pb[3 * tid + 1], z = pb[3 * tid + 2];
            sPn[pp][tid] = fmaf(z, z, fmaf(y, y, x * x));
            sA[pp][tid] = (f16x8){(_Float16)(-2.0f * x), (_Float16)(-2.0f * y),
                                  (_Float16)(-2.0f * z), (_Float16)1.0f,
                                  (_Float16)1.0f, (_Float16)0, (_Float16)0,
                                  (_Float16)0};
            x = tb[3 * tid + 0]; y = tb[3 * tid + 1]; z = tb[3 * tid + 2];
            const float tn = fmaf(z, z, fmaf(y, y, x * x));
            const _Float16 th = (_Float16)tn;                 // RTNE
            const _Float16 tl = (_Float16)(tn - (float)th);   // residual
            sB[pp][tid] = (f16x8){(_Float16)x, (_Float16)y, (_Float16)z,
                                  th, tl, (_Float16)0, (_Float16)0, (_Float16)0};
        }
        if (tid == 0) szero = (f16x8){};
    }
    __syncthreads();

    const int wave = tid >> 6;      // one wave = one patch
    const int lane = tid & 63;
    const int c    = lane & 15;     // col within tile
    const int quad = lane >> 4;
    const bool q0  = (quad == 0);
    const int pp   = wave;

    // B-frags once per wave; quads 1-3 point at the shared zero slot.
    f16x8 bfrag[16];
    float colmin[16];
#pragma unroll
    for (int jb = 0; jb < 16; ++jb) {
        const f16x8* addr = q0 ? &sB[pp][jb * 16 + c] : &szero;
        bfrag[jb] = *addr;
        colmin[jb] = 1e30f;
    }

    float sf = 0.0f;

#pragma unroll 1
    for (int ib = 0; ib < 16; ++ib) {
        // A-frag: one ds_read_b128, identical across quads (B zeros k>=8).
        const f16x8 af = sA[pp][ib * 16 + c];
        // C-init = pn for this lane's 4 rows (fp32, exact).
        const f32x4 pnv = *(const f32x4*)&sPn[pp][ib * 16 + quad * 4];

        float r0 = 1e30f, r1 = 1e30f, r2 = 1e30f, r3 = 1e30f;
#pragma unroll
        for (int jb = 0; jb < 16; jb += 2) {
            const f32x4 d1 = __builtin_amdgcn_mfma_f32_16x16x32_f16(
                af, bfrag[jb], pnv, 0, 0, 0);
            const f32x4 d2 = __builtin_amdgcn_mfma_f32_16x16x32_f16(
                af, bfrag[jb + 1], pnv, 0, 0, 0);
            // rowmin: v_min3 over two tiles at once
            r0 = fminf(r0, fminf(d1.x, d2.x));
            r1 = fminf(r1, fminf(d1.y, d2.y));
            r2 = fminf(r2, fminf(d1.z, d2.z));
            r3 = fminf(r3, fminf(d1.w, d2.w));
            // colmin: 2x v_min3 per tile
            const float t1 = fminf(fminf(d1.x, d1.y), d1.z);
            colmin[jb] = fminf(fminf(t1, d1.w), colmin[jb]);
            const float t2 = fminf(fminf(d2.x, d2.y), d2.z);
            colmin[jb + 1] = fminf(fminf(t2, d2.w), colmin[jb + 1]);
        }
        // rowmin across the 16 cols held by this quad's lanes.
#pragma unroll
        for (int dlt = 1; dlt < 16; dlt <<= 1) {
            r0 = fminf(r0, __shfl_xor(r0, dlt, 64));
            r1 = fminf(r1, __shfl_xor(r1, dlt, 64));
            r2 = fminf(r2, __shfl_xor(r2, dlt, 64));
            r3 = fminf(r3, __shfl_xor(r3, dlt, 64));
        }
        // each row duplicated across 16 lanes -> scale 1/16 at the end
        sf += fmaxf(r0, 0.0f) + fmaxf(r1, 0.0f) +
              fmaxf(r2, 0.0f) + fmaxf(r3, 0.0f);
    }

    // colmin: min across the 4 quads; each col duplicated x4 -> scale 1/4.
    float sb = 0.0f;
#pragma unroll
    for (int jb = 0; jb < 16; ++jb) {
        float v = colmin[jb];
        v = fminf(v, __shfl_xor(v, 16, 64));
        v = fminf(v, __shfl_xor(v, 32, 64));
        sb += fmaxf(v, 0.0f);
    }

    float tot = sf * (1.0f / 16.0f) + sb * (1.0f / 4.0f);
#pragma unroll
    for (int off = 32; off > 0; off >>= 1)
        tot += __shfl_down(tot, off, 64);
    if (lane == 0) partial[blockIdx.x * 4 + wave] = tot;
}

__global__ __launch_bounds__(256) void chamfer_reduce_kernel(
    const float* __restrict__ partial,
    float* __restrict__ out)
{
    __shared__ float red[4];
    const int tid = threadIdx.x;
    float s = 0.0f;
#pragma unroll
    for (int i = tid; i < NPATCH; i += 256) s += partial[i];
#pragma unroll
    for (int off = 32; off > 0; off >>= 1)
        s += __shfl_down(s, off, 64);
    if ((tid & 63) == 0) red[tid >> 6] = s;
    __syncthreads();
    if (tid == 0)
        out[0] = (red[0] + red[1] + red[2] + red[3]) *
                 (1.0f / ((float)NPTS * (float)NPATCH));
}

extern "C" void kernel_launch(void* const* d_in, const int* in_sizes, int n_in,
                              void* d_out, int out_size, void* d_ws, size_t ws_size,
                              hipStream_t stream) {
    const float* pred = (const float*)d_in[0];
    const float* tgt  = (const float*)d_in[1];
    float* partial    = (float*)d_ws;      // 2048 floats = 8 KB scratch
    float* out        = (float*)d_out;

    chamfer_mfma_kernel<<<NPATCH / 4, 256, 0, stream>>>(pred, tgt, partial);
    chamfer_reduce_kernel<<<1, 256, 0, stream>>>(partial, out);
}